// Round 1
// 691.192 us; speedup vs baseline: 1.0038x; 1.0038x over previous
//
#include <hip/hip_runtime.h>
#include <float.h>

#define H 1024
#define SEQ 2048
#define V 50257

// ---- output layout (flat, in return order) ----
#define OUT_CTX   50257            // context (H)
#define OUT_H0    (OUT_CTX + H)    // hidden[0] (H)
#define OUT_H1    (OUT_H0 + H)     // hidden[1] (H)
#define OUT_ATTN  (OUT_H1 + H)     // attn (SEQ)

// ---- ws layout (floats) ----
#define WS_H0     0        // h0 (1024)
#define WS_H1     1024     // h1 (1024)
#define WS_E      2048     // energies (2048)
#define WS_EPM    4096     // energies partial max (512)
#define WS_EPS    4608     // energies partial sumexp (512)
#define WS_CTX    5120     // context acc (1024)
#define WS_LOGITS 6144     // logits (50257)
#define WS_LPM    56448    // logits partial max (1006)
#define WS_LPS    57472    // logits partial sumexp (1006)
#define WS_LOGZ   58496    // logZ (1)

#define LOGITS_ROWS_PB 50
#define LOGITS_NB      ((V + LOGITS_ROWS_PB - 1) / LOGITS_ROWS_PB)  // 1006

__device__ __forceinline__ float dot4(float4 a, float4 b) {
  return a.x * b.x + a.y * b.y + a.z * b.z + a.w * b.w;
}

// butterfly: every lane ends with the full 64-lane sum
__device__ __forceinline__ float wave_allreduce_sum(float v) {
  #pragma unroll
  for (int off = 32; off > 0; off >>= 1) v += __shfl_xor(v, off);
  return v;
}

// 1) GRU layer 0: x = [emb[word], last_context] read directly (no prep pass).
//    One block per output element j; 6 waves = 6 row-dots.
__global__ __launch_bounds__(384) void gru0_kernel(
    const float* __restrict__ emb, const int* __restrict__ word,
    const float* __restrict__ last_context,
    const float* __restrict__ hprev,              // last_hidden[0]
    const float* __restrict__ W_ih,               // (3H, 2H)
    const float* __restrict__ W_hh,               // (3H, H)
    const float* __restrict__ b_ih, const float* __restrict__ b_hh,
    float* __restrict__ h_ws, float* __restrict__ h_out) {
  int j = blockIdx.x;
  int wave = threadIdx.x >> 6, lane = threadIdx.x & 63;
  __shared__ float parts[6];
  float acc = 0.0f;
  if (wave < 3) {
    const float4* wr = (const float4*)(W_ih + (size_t)(wave * H + j) * (2 * H));
    const float4* e4 = (const float4*)(emb + (size_t)word[0] * H);
    const float4* c4 = (const float4*)last_context;
    #pragma unroll
    for (int it = 0; it < 8; ++it) {
      int idx = it * 64 + lane;
      float4 xv = (it < 4) ? e4[idx] : c4[idx - 256];
      acc += dot4(wr[idx], xv);
    }
  } else {
    const float4* wr = (const float4*)(W_hh + (size_t)((wave - 3) * H + j) * H);
    const float4* hv = (const float4*)hprev;
    #pragma unroll
    for (int it = 0; it < 4; ++it) {
      int idx = it * 64 + lane;
      acc += dot4(wr[idx], hv[idx]);
    }
  }
  acc = wave_allreduce_sum(acc);
  if (lane == 0) parts[wave] = acc;
  __syncthreads();
  if (threadIdx.x == 0) {
    float gi_r = parts[0] + b_ih[j];
    float gi_z = parts[1] + b_ih[H + j];
    float gi_n = parts[2] + b_ih[2 * H + j];
    float gh_r = parts[3] + b_hh[j];
    float gh_z = parts[4] + b_hh[H + j];
    float gh_n = parts[5] + b_hh[2 * H + j];
    float r = 1.0f / (1.0f + expf(-(gi_r + gh_r)));
    float z = 1.0f / (1.0f + expf(-(gi_z + gh_z)));
    float n = tanhf(gi_n + r * gh_n);
    float hp = hprev[j];
    float hn = (1.0f - z) * n + z * hp;
    h_ws[j] = hn;
    h_out[j] = hn;
  }
}

// 2) GRU layer 1 (XDIM = H)
__global__ __launch_bounds__(384) void gru1_kernel(
    const float* __restrict__ x,                  // h0 (H)
    const float* __restrict__ hprev,              // last_hidden[1]
    const float* __restrict__ W_ih,               // (3H, H)
    const float* __restrict__ W_hh,               // (3H, H)
    const float* __restrict__ b_ih, const float* __restrict__ b_hh,
    float* __restrict__ h_ws, float* __restrict__ h_out) {
  int j = blockIdx.x;
  int wave = threadIdx.x >> 6, lane = threadIdx.x & 63;
  __shared__ float parts[6];
  const float* W   = (wave < 3) ? W_ih : W_hh;
  const float* vec = (wave < 3) ? x : hprev;
  int row = (wave < 3) ? wave : (wave - 3);
  const float4* wr = (const float4*)(W + (size_t)(row * H + j) * H);
  const float4* xv = (const float4*)vec;
  float acc = 0.0f;
  #pragma unroll
  for (int it = 0; it < 4; ++it) {
    int idx = it * 64 + lane;
    acc += dot4(wr[idx], xv[idx]);
  }
  acc = wave_allreduce_sum(acc);
  if (lane == 0) parts[wave] = acc;
  __syncthreads();
  if (threadIdx.x == 0) {
    float gi_r = parts[0] + b_ih[j];
    float gi_z = parts[1] + b_ih[H + j];
    float gi_n = parts[2] + b_ih[2 * H + j];
    float gh_r = parts[3] + b_hh[j];
    float gh_z = parts[4] + b_hh[H + j];
    float gh_n = parts[5] + b_hh[2 * H + j];
    float r = 1.0f / (1.0f + expf(-(gi_r + gh_r)));
    float z = 1.0f / (1.0f + expf(-(gi_z + gh_z)));
    float n = tanhf(gi_n + r * gh_n);
    float hp = hprev[j];
    float hn = (1.0f - z) * n + z * hp;
    h_ws[j] = hn;
    h_out[j] = hn;
  }
}

// 3) energies[s] = dot(enc[s], h1) + per-block softmax partials (max, sumexp).
//    Blocks 0..3 also zero the ctx accumulator (consumed 2 kernels later).
__global__ __launch_bounds__(256) void energies_kernel(
    const float* __restrict__ enc, const float* __restrict__ h1,
    float* __restrict__ energies, float* __restrict__ epm,
    float* __restrict__ eps, float* __restrict__ ctx) {
  int t = threadIdx.x;
  if (blockIdx.x < 4) ctx[blockIdx.x * 256 + t] = 0.0f;
  int wave = t >> 6, lane = t & 63;
  int s = blockIdx.x * 4 + wave;
  const float4* er = (const float4*)(enc + (size_t)s * H);
  const float4* hv = (const float4*)h1;
  float acc = 0.0f;
  #pragma unroll
  for (int it = 0; it < 4; ++it) {
    int idx = it * 64 + lane;
    acc += dot4(er[idx], hv[idx]);
  }
  acc = wave_allreduce_sum(acc);
  __shared__ float se[4];
  if (lane == 0) { se[wave] = acc; energies[s] = acc; }
  __syncthreads();
  if (t == 0) {
    float m = fmaxf(fmaxf(se[0], se[1]), fmaxf(se[2], se[3]));
    float ss = expf(se[0] - m) + expf(se[1] - m) + expf(se[2] - m) + expf(se[3] - m);
    epm[blockIdx.x] = m;
    eps[blockIdx.x] = ss;
  }
}

// 4) context: each block combines the 512 softmax partials (cheap, redundant),
//    recomputes attn for its 32-s slice, accumulates into ctx via atomics,
//    and (bx==0) writes the attn output.
__global__ __launch_bounds__(256) void context_kernel(
    const float* __restrict__ energies, const float* __restrict__ epm,
    const float* __restrict__ eps, const float* __restrict__ enc,
    float* __restrict__ ctx, float* __restrict__ attn_out) {
  __shared__ float red[256];
  __shared__ float satt[32];
  int t = threadIdx.x;
  float m = fmaxf(epm[t], epm[t + 256]);
  red[t] = m;
  __syncthreads();
  #pragma unroll
  for (int off = 128; off > 0; off >>= 1) {
    if (t < off) red[t] = fmaxf(red[t], red[t + off]);
    __syncthreads();
  }
  float M = red[0];
  __syncthreads();
  red[t] = eps[t] * expf(epm[t] - M) + eps[t + 256] * expf(epm[t + 256] - M);
  __syncthreads();
  #pragma unroll
  for (int off = 128; off > 0; off >>= 1) {
    if (t < off) red[t] += red[t + off];
    __syncthreads();
  }
  float Zinv = 1.0f / red[0];
  int s0 = blockIdx.y * 32;
  if (t < 32) satt[t] = expf(energies[s0 + t] - M) * Zinv;
  __syncthreads();
  int h2 = blockIdx.x * 512 + t * 2;
  float a0 = 0.0f, a1 = 0.0f;
  for (int i = 0; i < 32; ++i) {
    float a = satt[i];
    float2 p = *(const float2*)(enc + (size_t)(s0 + i) * H + h2);
    a0 += a * p.x;
    a1 += a * p.y;
  }
  atomicAdd(&ctx[h2], a0);
  atomicAdd(&ctx[h2 + 1], a1);
  if (blockIdx.x == 0 && t < 32) attn_out[s0 + t] = satt[t];
}

// 5) logits GEMV + fused LSE partials. 1006 blocks, each owns a contiguous
//    50-row band of W_out (400 KB). 4 waves/block, 2 rows in flight per wave
//    (16 outstanding dwordx4 loads), y staged once in LDS per block.
__global__ __launch_bounds__(256) void logits_kernel(
    const float* __restrict__ W_out, const float* __restrict__ b_out,
    const float* __restrict__ h1, const float* __restrict__ ctx,
    float* __restrict__ logits, float* __restrict__ lpm,
    float* __restrict__ lps) {
  __shared__ float y[2 * H];
  __shared__ float wm[4], wsv[4];
  int t = threadIdx.x;
  #pragma unroll
  for (int i = 0; i < 4; ++i) {
    int k = t + i * 256;
    y[k] = h1[k];
    y[H + k] = ctx[k];
  }
  __syncthreads();
  int wave = t >> 6, lane = t & 63;
  const float4* yv = (const float4*)y;
  int base = blockIdx.x * LOGITS_ROWS_PB;
  int rend = min(base + LOGITS_ROWS_PB, V);
  float m = -FLT_MAX, s = 0.0f;
  int r = base + wave;
  // paired rows (r, r+4), stride 8 per wave
  for (; r + 4 < rend; r += 8) {
    const float4* w0 = (const float4*)(W_out + (size_t)r * (2 * H));
    const float4* w1 = (const float4*)(W_out + (size_t)(r + 4) * (2 * H));
    float a0 = 0.0f, a1 = 0.0f;
    #pragma unroll
    for (int it = 0; it < 8; ++it) {
      int idx = it * 64 + lane;
      float4 yy = yv[idx];
      a0 += dot4(w0[idx], yy);
      a1 += dot4(w1[idx], yy);
    }
    #pragma unroll
    for (int off = 32; off > 0; off >>= 1) {
      a0 += __shfl_xor(a0, off);
      a1 += __shfl_xor(a1, off);
    }
    float l0 = a0 + b_out[r];
    float l1 = a1 + b_out[r + 4];
    if (lane == 0) { logits[r] = l0; logits[r + 4] = l1; }
    float nm = fmaxf(m, fmaxf(l0, l1));
    s = s * expf(m - nm) + expf(l0 - nm) + expf(l1 - nm);
    m = nm;
  }
  for (; r < rend; r += 4) {  // at most one leftover row per wave
    const float4* w0 = (const float4*)(W_out + (size_t)r * (2 * H));
    float a0 = 0.0f;
    #pragma unroll
    for (int it = 0; it < 8; ++it) {
      int idx = it * 64 + lane;
      a0 += dot4(w0[idx], yv[idx]);
    }
    a0 = wave_allreduce_sum(a0);
    float l0 = a0 + b_out[r];
    if (lane == 0) logits[r] = l0;
    float nm = fmaxf(m, l0);
    s = s * expf(m - nm) + expf(l0 - nm);
    m = nm;
  }
  if (lane == 0) { wm[wave] = m; wsv[wave] = s; }
  __syncthreads();
  if (t == 0) {
    float mb = fmaxf(fmaxf(wm[0], wm[1]), fmaxf(wm[2], wm[3]));
    float sb = wsv[0] * expf(wm[0] - mb) + wsv[1] * expf(wm[1] - mb) +
               wsv[2] * expf(wm[2] - mb) + wsv[3] * expf(wm[3] - mb);
    lpm[blockIdx.x] = mb;
    lps[blockIdx.x] = sb;
  }
}

// 6) combine 1006 block partials -> logZ
__global__ __launch_bounds__(256) void lse_final_kernel(
    const float* __restrict__ lpm, const float* __restrict__ lps,
    float* __restrict__ logZ) {
  __shared__ float red[256];
  int t = threadIdx.x;
  float m = -FLT_MAX;
  #pragma unroll
  for (int i = 0; i < 4; ++i) {
    int k = t + i * 256;
    if (k < LOGITS_NB) m = fmaxf(m, lpm[k]);
  }
  red[t] = m;
  __syncthreads();
  #pragma unroll
  for (int off = 128; off > 0; off >>= 1) {
    if (t < off) red[t] = fmaxf(red[t], red[t + off]);
    __syncthreads();
  }
  float M = red[0];
  __syncthreads();
  float s = 0.0f;
  #pragma unroll
  for (int i = 0; i < 4; ++i) {
    int k = t + i * 256;
    if (k < LOGITS_NB) s += lps[k] * expf(lpm[k] - M);
  }
  red[t] = s;
  __syncthreads();
  #pragma unroll
  for (int off = 128; off > 0; off >>= 1) {
    if (t < off) red[t] += red[t + off];
    __syncthreads();
  }
  if (t == 0) logZ[0] = M + logf(red[0]);
}

// 7) out[v] = logits[v] - logZ; copy context to out
__global__ __launch_bounds__(256) void finalize_kernel(
    const float* __restrict__ logits, const float* __restrict__ logZ,
    const float* __restrict__ ctx, float* __restrict__ out) {
  int v = blockIdx.x * 256 + threadIdx.x;
  float lz = logZ[0];
  if (v < V) out[v] = logits[v] - lz;
  if (v < H) out[OUT_CTX + v] = ctx[v];
}

extern "C" void kernel_launch(void* const* d_in, const int* in_sizes, int n_in,
                              void* d_out, int out_size, void* d_ws, size_t ws_size,
                              hipStream_t stream) {
  const int*   word         = (const int*)d_in[0];
  const float* last_context = (const float*)d_in[1];
  const float* last_hidden  = (const float*)d_in[2];
  const float* enc          = (const float*)d_in[3];
  const float* emb          = (const float*)d_in[4];
  const float* W_ih0        = (const float*)d_in[5];
  const float* W_hh0        = (const float*)d_in[6];
  const float* b_ih0        = (const float*)d_in[7];
  const float* b_hh0        = (const float*)d_in[8];
  const float* W_ih1        = (const float*)d_in[9];
  const float* W_hh1        = (const float*)d_in[10];
  const float* b_ih1        = (const float*)d_in[11];
  const float* b_hh1        = (const float*)d_in[12];
  const float* W_out        = (const float*)d_in[13];
  const float* b_out        = (const float*)d_in[14];
  float* out = (float*)d_out;

  float* ws       = (float*)d_ws;
  float* h0       = ws + WS_H0;
  float* h1       = ws + WS_H1;
  float* energies = ws + WS_E;
  float* epm      = ws + WS_EPM;
  float* eps      = ws + WS_EPS;
  float* ctx      = ws + WS_CTX;
  float* logits   = ws + WS_LOGITS;
  float* lpm      = ws + WS_LPM;
  float* lps      = ws + WS_LPS;
  float* logZ     = ws + WS_LOGZ;

  gru0_kernel<<<H, 384, 0, stream>>>(emb, word, last_context, last_hidden,
                                     W_ih0, W_hh0, b_ih0, b_hh0, h0, out + OUT_H0);
  gru1_kernel<<<H, 384, 0, stream>>>(h0, last_hidden + H, W_ih1, W_hh1,
                                     b_ih1, b_hh1, h1, out + OUT_H1);
  energies_kernel<<<SEQ / 4, 256, 0, stream>>>(enc, h1, energies, epm, eps, ctx);
  context_kernel<<<dim3(2, 64), 256, 0, stream>>>(energies, epm, eps, enc, ctx,
                                                  out + OUT_ATTN);
  logits_kernel<<<LOGITS_NB, 256, 0, stream>>>(W_out, b_out, h1, ctx, logits,
                                               lpm, lps);
  lse_final_kernel<<<1, 256, 0, stream>>>(lpm, lps, logZ);
  finalize_kernel<<<(V + 255) / 256, 256, 0, stream>>>(logits, logZ, ctx, out);
}

// Round 2
// 690.367 us; speedup vs baseline: 1.0050x; 1.0012x over previous
//
#include <hip/hip_runtime.h>
#include <float.h>

#define H 1024
#define SEQ 2048
#define V 50257

// ---- output layout (flat, in return order) ----
#define OUT_CTX   50257            // context (H)
#define OUT_H0    (OUT_CTX + H)    // hidden[0] (H)
#define OUT_H1    (OUT_H0 + H)     // hidden[1] (H)
#define OUT_ATTN  (OUT_H1 + H)     // attn (SEQ)

// ---- ws layout (floats) ----
#define WS_H0     0        // h0 (1024)
#define WS_H1     1024     // h1 (1024)
#define WS_E      2048     // energies (2048)
#define WS_EPM    4096     // energies partial max (128)
#define WS_EPS    4224     // energies partial sumexp (128)
#define WS_PC     4352     // partial context (128 x 1024)
#define WS_CTX    135424   // context (1024)
#define WS_LOGITS 136448   // logits (50257)
#define WS_LPM    186705   // logits partial max (1006)
#define WS_LPS    187711   // logits partial sumexp (1006)

#define EBLK      16                       // s-rows per energies block
#define ENB       (SEQ / EBLK)             // 128 energies blocks
#define LOGITS_ROWS_PB 50
#define LOGITS_NB ((V + LOGITS_ROWS_PB - 1) / LOGITS_ROWS_PB)  // 1006

__device__ __forceinline__ float dot4(float4 a, float4 b) {
  return a.x * b.x + a.y * b.y + a.z * b.z + a.w * b.w;
}

__device__ __forceinline__ float wave_allreduce_sum(float v) {
  #pragma unroll
  for (int off = 32; off > 0; off >>= 1) v += __shfl_xor(v, off);
  return v;
}

// 1) GRU layer 0: x = [emb[word], last_context] read directly.
__global__ __launch_bounds__(384) void gru0_kernel(
    const float* __restrict__ emb, const int* __restrict__ word,
    const float* __restrict__ last_context,
    const float* __restrict__ hprev,              // last_hidden[0]
    const float* __restrict__ W_ih,               // (3H, 2H)
    const float* __restrict__ W_hh,               // (3H, H)
    const float* __restrict__ b_ih, const float* __restrict__ b_hh,
    float* __restrict__ h_ws, float* __restrict__ h_out) {
  int j = blockIdx.x;
  int wave = threadIdx.x >> 6, lane = threadIdx.x & 63;
  __shared__ float parts[6];
  float acc = 0.0f;
  if (wave < 3) {
    const float4* wr = (const float4*)(W_ih + (size_t)(wave * H + j) * (2 * H));
    const float4* e4 = (const float4*)(emb + (size_t)word[0] * H);
    const float4* c4 = (const float4*)last_context;
    #pragma unroll
    for (int it = 0; it < 8; ++it) {
      int idx = it * 64 + lane;
      float4 xv = (it < 4) ? e4[idx] : c4[idx - 256];
      acc += dot4(wr[idx], xv);
    }
  } else {
    const float4* wr = (const float4*)(W_hh + (size_t)((wave - 3) * H + j) * H);
    const float4* hv = (const float4*)hprev;
    #pragma unroll
    for (int it = 0; it < 4; ++it) {
      int idx = it * 64 + lane;
      acc += dot4(wr[idx], hv[idx]);
    }
  }
  acc = wave_allreduce_sum(acc);
  if (lane == 0) parts[wave] = acc;
  __syncthreads();
  if (threadIdx.x == 0) {
    float gi_r = parts[0] + b_ih[j];
    float gi_z = parts[1] + b_ih[H + j];
    float gi_n = parts[2] + b_ih[2 * H + j];
    float gh_r = parts[3] + b_hh[j];
    float gh_z = parts[4] + b_hh[H + j];
    float gh_n = parts[5] + b_hh[2 * H + j];
    float r = 1.0f / (1.0f + expf(-(gi_r + gh_r)));
    float z = 1.0f / (1.0f + expf(-(gi_z + gh_z)));
    float n = tanhf(gi_n + r * gh_n);
    float hp = hprev[j];
    float hn = (1.0f - z) * n + z * hp;
    h_ws[j] = hn;
    h_out[j] = hn;
  }
}

// 2) GRU layer 1 (XDIM = H)
__global__ __launch_bounds__(384) void gru1_kernel(
    const float* __restrict__ x,                  // h0 (H)
    const float* __restrict__ hprev,              // last_hidden[1]
    const float* __restrict__ W_ih,               // (3H, H)
    const float* __restrict__ W_hh,               // (3H, H)
    const float* __restrict__ b_ih, const float* __restrict__ b_hh,
    float* __restrict__ h_ws, float* __restrict__ h_out) {
  int j = blockIdx.x;
  int wave = threadIdx.x >> 6, lane = threadIdx.x & 63;
  __shared__ float parts[6];
  const float* W   = (wave < 3) ? W_ih : W_hh;
  const float* vec = (wave < 3) ? x : hprev;
  int row = (wave < 3) ? wave : (wave - 3);
  const float4* wr = (const float4*)(W + (size_t)(row * H + j) * H);
  const float4* xv = (const float4*)vec;
  float acc = 0.0f;
  #pragma unroll
  for (int it = 0; it < 4; ++it) {
    int idx = it * 64 + lane;
    acc += dot4(wr[idx], xv[idx]);
  }
  acc = wave_allreduce_sum(acc);
  if (lane == 0) parts[wave] = acc;
  __syncthreads();
  if (threadIdx.x == 0) {
    float gi_r = parts[0] + b_ih[j];
    float gi_z = parts[1] + b_ih[H + j];
    float gi_n = parts[2] + b_ih[2 * H + j];
    float gh_r = parts[3] + b_hh[j];
    float gh_z = parts[4] + b_hh[H + j];
    float gh_n = parts[5] + b_hh[2 * H + j];
    float r = 1.0f / (1.0f + expf(-(gi_r + gh_r)));
    float z = 1.0f / (1.0f + expf(-(gi_z + gh_z)));
    float n = tanhf(gi_n + r * gh_n);
    float hp = hprev[j];
    float hn = (1.0f - z) * n + z * hp;
    h_ws[j] = hn;
    h_out[j] = hn;
  }
}

// 3) energies + partial context. Each block owns 16 s-rows:
//    e[s] = dot(enc[s], h1); (m_b, s_b) online partials;
//    c_b[h] = sum_{s in b} exp(e_s - m_b) * enc[s][h]  (enc rows are L1/L2-hot).
__global__ __launch_bounds__(256) void energies_pctx_kernel(
    const float* __restrict__ enc, const float* __restrict__ h1,
    float* __restrict__ energies, float* __restrict__ epm,
    float* __restrict__ eps, float* __restrict__ pctx) {
  __shared__ float se[EBLK];
  __shared__ float sw[EBLK];
  int t = threadIdx.x;
  int wave = t >> 6, lane = t & 63;
  int s0 = blockIdx.x * EBLK;
  const float4* hv = (const float4*)h1;
  #pragma unroll
  for (int k = 0; k < 4; ++k) {
    int s = s0 + wave * 4 + k;
    const float4* er = (const float4*)(enc + (size_t)s * H);
    float acc = 0.0f;
    #pragma unroll
    for (int it = 0; it < 4; ++it) {
      int idx = it * 64 + lane;
      acc += dot4(er[idx], hv[idx]);
    }
    acc = wave_allreduce_sum(acc);
    if (lane == 0) { se[wave * 4 + k] = acc; energies[s] = acc; }
  }
  __syncthreads();
  // block-local max (redundant per thread; broadcast shared reads)
  float mb = se[0];
  #pragma unroll
  for (int i = 1; i < EBLK; ++i) mb = fmaxf(mb, se[i]);
  if (t < EBLK) sw[t] = expf(se[t] - mb);
  __syncthreads();
  if (t == 0) {
    float sb = 0.0f;
    #pragma unroll
    for (int i = 0; i < EBLK; ++i) sb += sw[i];
    epm[blockIdx.x] = mb;
    eps[blockIdx.x] = sb;
  }
  // partial context: thread t owns float4 h-group t (h = 4t..4t+3)
  float4 acc = make_float4(0.f, 0.f, 0.f, 0.f);
  #pragma unroll
  for (int i = 0; i < EBLK; ++i) {
    float w = sw[i];
    float4 p = ((const float4*)(enc + (size_t)(s0 + i) * H))[t];
    acc.x += w * p.x; acc.y += w * p.y; acc.z += w * p.z; acc.w += w * p.w;
  }
  ((float4*)(pctx + (size_t)blockIdx.x * H))[t] = acc;
}

// 4) combine: global (M, Z) from 128 partials; blocks 0-3 rescale+sum the
//    partial contexts -> ctx (ws + out); blocks 4-11 write attn output.
__global__ __launch_bounds__(256) void combine_kernel(
    const float* __restrict__ energies, const float* __restrict__ epm,
    const float* __restrict__ eps, const float* __restrict__ pctx,
    float* __restrict__ ctx, float* __restrict__ out) {
  __shared__ float red[256];
  __shared__ float swg[ENB];
  int t = threadIdx.x;
  red[t] = (t < ENB) ? epm[t] : -FLT_MAX;
  __syncthreads();
  #pragma unroll
  for (int off = 128; off > 0; off >>= 1) {
    if (t < off) red[t] = fmaxf(red[t], red[t + off]);
    __syncthreads();
  }
  float M = red[0];
  __syncthreads();
  red[t] = (t < ENB) ? eps[t] * expf(epm[t] - M) : 0.0f;
  __syncthreads();
  #pragma unroll
  for (int off = 128; off > 0; off >>= 1) {
    if (t < off) red[t] += red[t + off];
    __syncthreads();
  }
  float Z = red[0];
  if (blockIdx.x < 4) {
    if (t < ENB) swg[t] = expf(epm[t] - M) / Z;
    __syncthreads();
    int h = blockIdx.x * 256 + t;
    float acc = 0.0f;
    #pragma unroll 8
    for (int b = 0; b < ENB; ++b) acc += swg[b] * pctx[(size_t)b * H + h];
    ctx[h] = acc;
    out[OUT_CTX + h] = acc;
  } else {
    int s = (blockIdx.x - 4) * 256 + t;
    out[OUT_ATTN + s] = expf(energies[s] - M) / Z;
  }
}

// 5) logits GEMV + fused LSE partials. 1006 blocks x 50-row contiguous bands,
//    4 waves/block, 2 rows in flight per wave, y staged once in LDS.
__global__ __launch_bounds__(256) void logits_kernel(
    const float* __restrict__ W_out, const float* __restrict__ b_out,
    const float* __restrict__ h1, const float* __restrict__ ctx,
    float* __restrict__ logits, float* __restrict__ lpm,
    float* __restrict__ lps) {
  __shared__ float y[2 * H];
  __shared__ float wm[4], wsv[4];
  int t = threadIdx.x;
  #pragma unroll
  for (int i = 0; i < 4; ++i) {
    int k = t + i * 256;
    y[k] = h1[k];
    y[H + k] = ctx[k];
  }
  __syncthreads();
  int wave = t >> 6, lane = t & 63;
  const float4* yv = (const float4*)y;
  int base = blockIdx.x * LOGITS_ROWS_PB;
  int rend = min(base + LOGITS_ROWS_PB, V);
  float m = -FLT_MAX, s = 0.0f;
  int r = base + wave;
  for (; r + 4 < rend; r += 8) {
    const float4* w0 = (const float4*)(W_out + (size_t)r * (2 * H));
    const float4* w1 = (const float4*)(W_out + (size_t)(r + 4) * (2 * H));
    float a0 = 0.0f, a1 = 0.0f;
    #pragma unroll
    for (int it = 0; it < 8; ++it) {
      int idx = it * 64 + lane;
      float4 yy = yv[idx];
      a0 += dot4(w0[idx], yy);
      a1 += dot4(w1[idx], yy);
    }
    #pragma unroll
    for (int off = 32; off > 0; off >>= 1) {
      a0 += __shfl_xor(a0, off);
      a1 += __shfl_xor(a1, off);
    }
    float l0 = a0 + b_out[r];
    float l1 = a1 + b_out[r + 4];
    if (lane == 0) { logits[r] = l0; logits[r + 4] = l1; }
    float nm = fmaxf(m, fmaxf(l0, l1));
    s = s * expf(m - nm) + expf(l0 - nm) + expf(l1 - nm);
    m = nm;
  }
  for (; r < rend; r += 4) {
    const float4* w0 = (const float4*)(W_out + (size_t)r * (2 * H));
    float a0 = 0.0f;
    #pragma unroll
    for (int it = 0; it < 8; ++it) {
      int idx = it * 64 + lane;
      a0 += dot4(w0[idx], yv[idx]);
    }
    a0 = wave_allreduce_sum(a0);
    float l0 = a0 + b_out[r];
    if (lane == 0) logits[r] = l0;
    float nm = fmaxf(m, l0);
    s = s * expf(m - nm) + expf(l0 - nm);
    m = nm;
  }
  if (lane == 0) { wm[wave] = m; wsv[wave] = s; }
  __syncthreads();
  if (t == 0) {
    float mb = fmaxf(fmaxf(wm[0], wm[1]), fmaxf(wm[2], wm[3]));
    float sb = wsv[0] * expf(wm[0] - mb) + wsv[1] * expf(wm[1] - mb) +
               wsv[2] * expf(wm[2] - mb) + wsv[3] * expf(wm[3] - mb);
    lpm[blockIdx.x] = mb;
    lps[blockIdx.x] = sb;
  }
}

// 6) finalize: each block redundantly combines the 1006 LSE partials -> logZ,
//    then out[v] = logits[v] - logZ.  (ctx/attn already written by combine.)
__global__ __launch_bounds__(256) void finalize_kernel(
    const float* __restrict__ logits, const float* __restrict__ lpm,
    const float* __restrict__ lps, float* __restrict__ out) {
  __shared__ float red[256];
  int t = threadIdx.x;
  float m = -FLT_MAX;
  #pragma unroll
  for (int i = 0; i < 4; ++i) {
    int k = t + i * 256;
    if (k < LOGITS_NB) m = fmaxf(m, lpm[k]);
  }
  red[t] = m;
  __syncthreads();
  #pragma unroll
  for (int off = 128; off > 0; off >>= 1) {
    if (t < off) red[t] = fmaxf(red[t], red[t + off]);
    __syncthreads();
  }
  float M = red[0];
  __syncthreads();
  float s = 0.0f;
  #pragma unroll
  for (int i = 0; i < 4; ++i) {
    int k = t + i * 256;
    if (k < LOGITS_NB) s += lps[k] * expf(lpm[k] - M);
  }
  red[t] = s;
  __syncthreads();
  #pragma unroll
  for (int off = 128; off > 0; off >>= 1) {
    if (t < off) red[t] += red[t + off];
    __syncthreads();
  }
  float logZ = M + logf(red[0]);
  int v = blockIdx.x * 256 + t;
  if (v < V) out[v] = logits[v] - logZ;
}

extern "C" void kernel_launch(void* const* d_in, const int* in_sizes, int n_in,
                              void* d_out, int out_size, void* d_ws, size_t ws_size,
                              hipStream_t stream) {
  const int*   word         = (const int*)d_in[0];
  const float* last_context = (const float*)d_in[1];
  const float* last_hidden  = (const float*)d_in[2];
  const float* enc          = (const float*)d_in[3];
  const float* emb          = (const float*)d_in[4];
  const float* W_ih0        = (const float*)d_in[5];
  const float* W_hh0        = (const float*)d_in[6];
  const float* b_ih0        = (const float*)d_in[7];
  const float* b_hh0        = (const float*)d_in[8];
  const float* W_ih1        = (const float*)d_in[9];
  const float* W_hh1        = (const float*)d_in[10];
  const float* b_ih1        = (const float*)d_in[11];
  const float* b_hh1        = (const float*)d_in[12];
  const float* W_out        = (const float*)d_in[13];
  const float* b_out        = (const float*)d_in[14];
  float* out = (float*)d_out;

  float* ws       = (float*)d_ws;
  float* h0       = ws + WS_H0;
  float* h1       = ws + WS_H1;
  float* energies = ws + WS_E;
  float* epm      = ws + WS_EPM;
  float* eps      = ws + WS_EPS;
  float* pctx     = ws + WS_PC;
  float* ctx      = ws + WS_CTX;
  float* logits   = ws + WS_LOGITS;
  float* lpm      = ws + WS_LPM;
  float* lps      = ws + WS_LPS;

  gru0_kernel<<<H, 384, 0, stream>>>(emb, word, last_context, last_hidden,
                                     W_ih0, W_hh0, b_ih0, b_hh0, h0, out + OUT_H0);
  gru1_kernel<<<H, 384, 0, stream>>>(h0, last_hidden + H, W_ih1, W_hh1,
                                     b_ih1, b_hh1, h1, out + OUT_H1);
  energies_pctx_kernel<<<ENB, 256, 0, stream>>>(enc, h1, energies, epm, eps, pctx);
  combine_kernel<<<12, 256, 0, stream>>>(energies, epm, eps, pctx, ctx, out);
  logits_kernel<<<LOGITS_NB, 256, 0, stream>>>(W_out, b_out, h1, ctx, logits,
                                               lpm, lps);
  finalize_kernel<<<(V + 255) / 256, 256, 0, stream>>>(logits, lpm, lps, out);
}